// Round 8
// baseline (2967.099 us; speedup 1.0000x reference)
//
#include <hip/hip_runtime.h>
#include <hip/hip_bf16.h>
#include <stdint.h>

#define B 16
#define H 512
#define L 256
#define TE 512
#define TD 256
#define NV 32000

typedef __attribute__((ext_vector_type(8))) __bf16 bf16x8;
typedef __attribute__((ext_vector_type(4))) float f32x4;
typedef __attribute__((ext_vector_type(8))) unsigned short u16x8;
typedef __attribute__((ext_vector_type(4))) unsigned short u16x4;
typedef unsigned short u16;
typedef unsigned long long u64;

__device__ __forceinline__ u16 f2bf(float f) {
  unsigned u = __float_as_uint(f);
  u += 0x7fffu + ((u >> 16) & 1u);   // RNE
  return (u16)(u >> 16);
}
__device__ __forceinline__ float fast_sigmoid(float x) {
  return __builtin_amdgcn_rcpf(1.f + __expf(-x));
}
__device__ __forceinline__ float fast_tanh(float x) {
  float e = __expf(2.f * x);
  return 1.f - 2.f * __builtin_amdgcn_rcpf(e + 1.f);
}

__device__ __forceinline__ u16x8 pack8(float4 a, float4 c) {
  u16x8 r;
  r[0] = f2bf(a.x); r[1] = f2bf(a.y); r[2] = f2bf(a.z); r[3] = f2bf(a.w);
  r[4] = f2bf(c.x); r[5] = f2bf(c.y); r[6] = f2bf(c.z); r[7] = f2bf(c.w);
  return r;
}

// ---------------- f32 -> bf16 convert ----------------
__global__ __launch_bounds__(256) void k_f2bf(const float* __restrict__ in,
                                              u16* __restrict__ outp, long n) {
  long i = ((long)blockIdx.x * 256 + threadIdx.x) * 8;
  if (i + 8 > n) return;
  float4 a = *(const float4*)&in[i];
  float4 c = *(const float4*)&in[i + 4];
  *(u16x8*)&outp[i] = pack8(a, c);
}

// ---------------- embedding gather -> bf16 ----------------
__global__ __launch_bounds__(256) void k_gather(const float* __restrict__ emb,
                                                const int* __restrict__ ids,
                                                u16* __restrict__ X, int rows) {
  int gid = blockIdx.x * 256 + threadIdx.x;
  int m = gid >> 6, seg = gid & 63;           // 64 segs * 8 = 512 cols
  if (m >= rows) return;
  long src = (long)ids[m] * H + seg * 8;
  float4 a = *(const float4*)&emb[src];
  float4 c = *(const float4*)&emb[src + 4];
  *(u16x8*)&X[(long)m * H + seg * 8] = pack8(a, c);
}

// ---------------- bf16 MFMA GEMM, C = A(MxK) * B^T(NxK) + bias ----------------
__global__ __launch_bounds__(256) void k_gemm_bt(const u16* __restrict__ A,
                                                 const u16* __restrict__ Bw,
                                                 const float* __restrict__ bias,
                                                 float* __restrict__ C,
                                                 int M, int N, int K) {
  constexpr int LDSK = 72;
  __shared__ u16 Al[128 * LDSK];
  __shared__ u16 Bl[128 * LDSK];
  const int tid = threadIdx.x;
  const int lane = tid & 63;
  const int wave = tid >> 6;
  const int wr = (wave >> 1) * 64, wc = (wave & 1) * 64;
  const long tM = (long)blockIdx.y * 128, tN = (long)blockIdx.x * 128;
  const int r32 = tid >> 3;
  const int c8 = (tid & 7) * 8;
  const u16* Ag = A + (tM + r32) * (long)K + c8;
  const u16* Bg = Bw + (tN + r32) * (long)K + c8;
  const int fr = lane & 15;
  const int fq = lane >> 4;
  f32x4 acc[4][4] = {};

  for (int kb = 0; kb < K; kb += 64) {
    u16x8 ta0 = *(const u16x8*)(Ag + kb);
    u16x8 ta1 = *(const u16x8*)(Ag + 32 * (long)K + kb);
    u16x8 ta2 = *(const u16x8*)(Ag + 64 * (long)K + kb);
    u16x8 ta3 = *(const u16x8*)(Ag + 96 * (long)K + kb);
    u16x8 tb0 = *(const u16x8*)(Bg + kb);
    u16x8 tb1 = *(const u16x8*)(Bg + 32 * (long)K + kb);
    u16x8 tb2 = *(const u16x8*)(Bg + 64 * (long)K + kb);
    u16x8 tb3 = *(const u16x8*)(Bg + 96 * (long)K + kb);
    __syncthreads();
    *(u16x8*)&Al[(r32 +  0) * LDSK + c8] = ta0;
    *(u16x8*)&Al[(r32 + 32) * LDSK + c8] = ta1;
    *(u16x8*)&Al[(r32 + 64) * LDSK + c8] = ta2;
    *(u16x8*)&Al[(r32 + 96) * LDSK + c8] = ta3;
    *(u16x8*)&Bl[(r32 +  0) * LDSK + c8] = tb0;
    *(u16x8*)&Bl[(r32 + 32) * LDSK + c8] = tb1;
    *(u16x8*)&Bl[(r32 + 64) * LDSK + c8] = tb2;
    *(u16x8*)&Bl[(r32 + 96) * LDSK + c8] = tb3;
    __syncthreads();
#pragma unroll
    for (int ks = 0; ks < 2; ks++) {
      const int kcol = ks * 32 + fq * 8;
      bf16x8 av[4], bv[4];
#pragma unroll
      for (int mi = 0; mi < 4; mi++)
        av[mi] = __builtin_bit_cast(bf16x8, *(const u16x8*)&Al[(wr + mi * 16 + fr) * LDSK + kcol]);
#pragma unroll
      for (int ni = 0; ni < 4; ni++)
        bv[ni] = __builtin_bit_cast(bf16x8, *(const u16x8*)&Bl[(wc + ni * 16 + fr) * LDSK + kcol]);
#pragma unroll
      for (int mi = 0; mi < 4; mi++)
#pragma unroll
        for (int ni = 0; ni < 4; ni++)
          acc[mi][ni] = __builtin_amdgcn_mfma_f32_16x16x32_bf16(av[mi], bv[ni], acc[mi][ni], 0, 0, 0);
    }
  }
#pragma unroll
  for (int mi = 0; mi < 4; mi++) {
    long row = tM + wr + mi * 16 + fq * 4;
#pragma unroll
    for (int ni = 0; ni < 4; ni++) {
      long col = tN + wc + ni * 16 + fr;
      float bs = bias[col];
#pragma unroll
      for (int r = 0; r < 4; r++)
        C[(row + r) * (long)N + col] = acc[mi][ni][r] + bs;
    }
  }
}

// ---------------- persistent GRU v8: compute/IO wave split -------------------
// waves 0-1 (cw): poll->stage->MFMA->gates->publish; NO other VMEM in flight.
// waves 2-3 (iw): prefetch gx(t+1)->gx_lds, drain out(t-1) out_lds->global.
template <bool ENC, int HD, int T>
__global__ __launch_bounds__(256) void k_gru8(const float* __restrict__ GX,   // [B*T][3*HD]
                                              const float* __restrict__ Whh,  // [3*HD][HD]
                                              const float* __restrict__ bhh,
                                              const int* __restrict__ lens,
                                              u64* __restrict__ Hbuf,         // [2][16][HD/2] tagged
                                              const float* __restrict__ h0f,  // DEC: fp32 z
                                              float* __restrict__ out_f32,    // ENC: [B][T][HD]
                                              u16* __restrict__ out_bf,       // DEC: [B*T][HD]
                                              float* __restrict__ hlast) {    // ENC: [B][HD]
  constexpr int UPW = 32;
  constexpr int ROWS = 3 * UPW;        // 96 gate rows per WG
  constexpr int LDH = HD + 8;
  constexpr int WPB = HD / 2;          // 8B words per batch row
  constexpr int NWORD = 16 * WPB;
  constexpr int PW = NWORD / 128;      // words polled per cw thread (enc 32, dec 16)
  __shared__ u16 w_lds[ROWS][LDH];     // tile-reordered: row (wv*3+g)*16+fr
  __shared__ u16 h_lds[16][LDH];
  __shared__ float gx_lds[2][3][16][33];
  __shared__ float out_lds[2][16][33];

  const int tid = threadIdx.x;
  const int u0 = blockIdx.x * UPW;
  const int lane = tid & 63, wv = tid >> 6;
  const int fr = lane & 15, fq = lane >> 4;
  const bool cw = wv < 2;
  const int ct = tid & 127;            // index within cw / iw half
  const int u = u0 + wv * 16 + fr;     // cw lane's unit

  // one-time: Whh slice -> bf16 LDS, tile-reordered (all 256 threads)
  for (int i = tid; i < ROWS * HD / 4; i += 256) {
    int rr = i / (HD / 4), c = (i % (HD / 4)) * 4;
    int tt = rr >> 4, fr_ = rr & 15;
    int grow = (tt % 3) * HD + u0 + (tt / 3) * 16 + fr_;
    float4 v = *(const float4*)&Whh[(long)grow * HD + c];
    u16x4 p; p[0] = f2bf(v.x); p[1] = f2bf(v.y); p[2] = f2bf(v.z); p[3] = f2bf(v.w);
    *(u16x4*)&w_lds[rr][c] = p;
  }
  int tmax = 1;
#pragma unroll
  for (int i = 0; i < 16; i++) tmax = max(tmax, lens[i]);

  float bh[3], hold[4];
  int len4[4];
#pragma unroll
  for (int g = 0; g < 3; g++) bh[g] = cw ? bhh[g * HD + u] : 0.f;
#pragma unroll
  for (int r = 0; r < 4; r++) {
    len4[r] = cw ? lens[fq * 4 + r] : 0;
    hold[r] = (ENC || !cw) ? 0.f : h0f[(fq * 4 + r) * HD + u];
  }
  // iw prologue: gx(0) -> gx_lds[0]
  if (!cw) {
    const int b = ct >> 3, c0 = (ct & 7) * 4;
#pragma unroll
    for (int g = 0; g < 3; g++) {
      float4 v = *(const float4*)&GX[((size_t)b * T) * 3 * HD + g * HD + u0 + c0];
      gx_lds[0][g][b][c0 + 0] = v.x; gx_lds[0][g][b][c0 + 1] = v.y;
      gx_lds[0][g][b][c0 + 2] = v.z; gx_lds[0][g][b][c0 + 3] = v.w;
    }
  }
  __syncthreads();

  for (int t = 0; ; t++) {
    const int cb_ = t & 1, nb_ = (t + 1) & 1;
    if (cw) {
      // ---- cw: coalesced poll of tagged h words, stage to LDS ----
      const u64* Hc = Hbuf + (size_t)cb_ * NWORD;
      const unsigned want = (unsigned)t;
      u64 vv[PW];
#pragma unroll
      for (int i = 0; i < PW; i++)
        vv[i] = __hip_atomic_load(&Hc[i * 128 + ct], __ATOMIC_RELAXED, __HIP_MEMORY_SCOPE_AGENT);
      for (;;) {
        bool ok = true;
#pragma unroll
        for (int i = 0; i < PW; i++) ok &= ((unsigned)(vv[i] >> 32) == want);
        if (ok) break;
#pragma unroll
        for (int i = 0; i < PW; i++)
          if ((unsigned)(vv[i] >> 32) != want)
            vv[i] = __hip_atomic_load(&Hc[i * 128 + ct], __ATOMIC_RELAXED, __HIP_MEMORY_SCOPE_AGENT);
      }
#pragma unroll
      for (int i = 0; i < PW; i++) {
        int w = i * 128 + ct;
        *(unsigned*)&h_lds[w / WPB][(w % WPB) * 2] = (unsigned)vv[i];
      }
    } else {
      // ---- iw: drain out(t-1), prefetch gx(t+1) ----
      const int b = ct >> 3;
      if (t > 0) {
        const int pb = (t - 1) & 1;
        const float* ol = &out_lds[pb][b][0];
        if constexpr (ENC) {
          const int c0 = (ct & 7) * 4;
          float4 o = make_float4(ol[c0], ol[c0 + 1], ol[c0 + 2], ol[c0 + 3]);
          *(float4*)&out_f32[((size_t)b * T + (t - 1)) * HD + u0 + c0] = o;
        } else {
          const int w0 = (ct & 7) * 4;
          uint2 o;
          o.x = ((unsigned)f2bf(ol[w0 + 1]) << 16) | f2bf(ol[w0]);
          o.y = ((unsigned)f2bf(ol[w0 + 3]) << 16) | f2bf(ol[w0 + 2]);
          *(uint2*)&out_bf[((size_t)b * T + (t - 1)) * HD + u0 + w0] = o;
        }
      }
      if (t + 1 < tmax) {
        const int c0 = (ct & 7) * 4;
#pragma unroll
        for (int g = 0; g < 3; g++) {
          float4 v = *(const float4*)&GX[((size_t)b * T + t + 1) * 3 * HD + g * HD + u0 + c0];
          gx_lds[nb_][g][b][c0 + 0] = v.x; gx_lds[nb_][g][b][c0 + 1] = v.y;
          gx_lds[nb_][g][b][c0 + 2] = v.z; gx_lds[nb_][g][b][c0 + 3] = v.w;
        }
      }
    }
    __syncthreads();                   // h staged; gx(t) available
    if (cw) {
      // ---- MFMA: 3 gate tiles, shared A-fragment ----
      f32x4 accg[3] = {};
#pragma unroll
      for (int kk = 0; kk < HD / 32; kk++) {
        int kc = kk * 32 + fq * 8;
        bf16x8 av = __builtin_bit_cast(bf16x8, *(const u16x8*)&h_lds[fr][kc]);
#pragma unroll
        for (int g = 0; g < 3; g++) {
          bf16x8 bv = __builtin_bit_cast(bf16x8,
              *(const u16x8*)&w_lds[(wv * 3 + g) * 16 + fr][kc]);
          accg[g] = __builtin_amdgcn_mfma_f32_16x16x32_bf16(av, bv, accg[g], 0, 0, 0);
        }
      }
      // ---- in-lane gates + publish + out_lds ----
      u64* Hn = Hbuf + (size_t)nb_ * NWORD;
#pragma unroll
      for (int r = 0; r < 4; r++) {
        const int bb = fq * 4 + r;
        const bool val = t < len4[r];
        const int uc = wv * 16 + fr;
        float rr_ = fast_sigmoid(accg[0][r] + bh[0] + gx_lds[cb_][0][bb][uc]);
        float zz  = fast_sigmoid(accg[1][r] + bh[1] + gx_lds[cb_][1][bb][uc]);
        float nn  = fast_tanh(gx_lds[cb_][2][bb][uc] + rr_ * (accg[2][r] + bh[2]));
        float hnew = (1.f - zz) * nn + zz * hold[r];
        float hk = val ? hnew : hold[r];
        hold[r] = hk;
        out_lds[cb_][bb][uc] = val ? hnew : 0.f;
        float sh = __shfl_xor(hk, 1);            // partner unit's h
        if (!(fr & 1)) {
          u64 pw = ((u64)(unsigned)(t + 1) << 32) |
                   ((unsigned)f2bf(sh) << 16) | f2bf(hk);
          __hip_atomic_store(&Hn[(size_t)bb * WPB + ((unsigned)u >> 1)], pw,
                             __ATOMIC_RELAXED, __HIP_MEMORY_SCOPE_AGENT);
        }
      }
    }
    __syncthreads();                   // out_lds(t) ready for iw
    if (t + 1 >= tmax) break;
  }

  // ---- epilogue ----
  if (cw) {
    if constexpr (ENC) {
#pragma unroll
      for (int r = 0; r < 4; r++) hlast[(fq * 4 + r) * HD + u] = hold[r];
    }
  } else {
    // final out(tmax-1)
    const int b = ct >> 3;
    const int pb = (tmax - 1) & 1;
    const float* ol = &out_lds[pb][b][0];
    if constexpr (ENC) {
      const int c0 = (ct & 7) * 4;
      float4 o = make_float4(ol[c0], ol[c0 + 1], ol[c0 + 2], ol[c0 + 3]);
      *(float4*)&out_f32[((size_t)b * T + (tmax - 1)) * HD + u0 + c0] = o;
    } else {
      const int w0 = (ct & 7) * 4;
      uint2 o;
      o.x = ((unsigned)f2bf(ol[w0 + 1]) << 16) | f2bf(ol[w0]);
      o.y = ((unsigned)f2bf(ol[w0 + 3]) << 16) | f2bf(ol[w0 + 2]);
      *(uint2*)&out_bf[((size_t)b * T + (tmax - 1)) * HD + u0 + w0] = o;
    }
  }
  if constexpr (ENC) {
    float4 z4 = make_float4(0.f, 0.f, 0.f, 0.f);
    for (int bb = 0; bb < 16; bb++)
      for (int x = tid; x < (T - tmax) * HD / 4; x += 256) {
        int t2 = tmax + (x * 4) / HD, c = (x * 4) % HD;
        *(float4*)&out_f32[((size_t)bb * T + t2) * HD + c] = z4;
      }
  } else {
    u16x8 z8 = {};
    for (int bb = 0; bb < 16; bb++)
      for (int x = tid; x < (T - tmax) * HD / 8; x += 256) {
        int t2 = tmax + (x * 8) / HD, c = (x * 8) % HD;
        *(u16x8*)&out_bf[((size_t)bb * T + t2) * HD + c] = z8;
      }
  }
}

// ---------------- attention pooling + mu/sigma/z + dec_max_len ----------------
__global__ __launch_bounds__(256) void k_middle(const float* __restrict__ out_enc,
                                                const float* __restrict__ hlast,
                                                const int* __restrict__ enc_len,
                                                const float* __restrict__ W_mu,
                                                const float* __restrict__ b_mu,
                                                const float* __restrict__ W_ls,
                                                const float* __restrict__ b_ls,
                                                const float* __restrict__ noise,
                                                const int* __restrict__ dec_len,
                                                float* __restrict__ out_tail,
                                                float* __restrict__ zf,
                                                u64* __restrict__ hbw) {
  const int b = blockIdx.x, tid = threadIdx.x;
  __shared__ float last[H], first[H], sfw[TE], sbw[TE], alpha[TE], sem[H];
  __shared__ float redA[256], redB[256];
  __shared__ u16 zbf[L];
  const int len = enc_len[b];
  for (int i = tid; i < H; i += 256) {
    last[i] = hlast[b * H + i];
    first[i] = out_enc[((size_t)b * TE) * H + i];
  }
  __syncthreads();
  for (int t = tid; t < TE; t += 256) {
    float afw = 0.f, abw = 0.f;
    if (t < len) {
      const float4* op = (const float4*)&out_enc[((size_t)b * TE + t) * H];
      for (int i = 0; i < H / 4; i++) {
        float4 o = op[i];
        float4 l = *(const float4*)&last[i * 4];
        float4 f = *(const float4*)&first[i * 4];
        afw += o.x * l.x + o.y * l.y + o.z * l.z + o.w * l.w;
        abw += o.x * f.x + o.y * f.y + o.z * f.z + o.w * f.w;
      }
    }
    sfw[t] = afw; sbw[t] = abw;
  }
  __syncthreads();
  float mfw = -3e38f, mbw = -3e38f;
  for (int t = tid; t < len; t += 256) { mfw = fmaxf(mfw, sfw[t]); mbw = fmaxf(mbw, sbw[t]); }
  redA[tid] = mfw; redB[tid] = mbw; __syncthreads();
  for (int s = 128; s > 0; s >>= 1) {
    if (tid < s) { redA[tid] = fmaxf(redA[tid], redA[tid + s]); redB[tid] = fmaxf(redB[tid], redB[tid + s]); }
    __syncthreads();
  }
  const float Mfw = redA[0], Mbw = redB[0];
  __syncthreads();
  float tfw = 0.f, tbw = 0.f;
  for (int t = tid; t < len; t += 256) {
    float e1 = expf(sfw[t] - Mfw); sfw[t] = e1; tfw += e1;
    float e2 = expf(sbw[t] - Mbw); sbw[t] = e2; tbw += e2;
  }
  redA[tid] = tfw; redB[tid] = tbw; __syncthreads();
  for (int s = 128; s > 0; s >>= 1) {
    if (tid < s) { redA[tid] += redA[tid + s]; redB[tid] += redB[tid + s]; }
    __syncthreads();
  }
  const float ifw = 0.5f / redA[0], ibw = 0.5f / redB[0];
  __syncthreads();
  for (int t = tid; t < TE; t += 256) alpha[t] = (t < len) ? (sfw[t] * ifw + sbw[t] * ibw) : 0.f;
  __syncthreads();
  for (int d = tid; d < H; d += 256) {
    float s = 0.f;
    for (int t = 0; t < len; t++) s += alpha[t] * out_enc[((size_t)b * TE + t) * H + d];
    sem[d] = s;
  }
  __syncthreads();
  {
    const int j = tid;  // 256 == L
    const float4* wm = (const float4*)&W_mu[(size_t)j * 2 * H];
    const float4* wl = (const float4*)&W_ls[(size_t)j * 2 * H];
    float am = 0.f, al = 0.f;
    for (int i = 0; i < H / 4; i++) {
      float4 hh = *(const float4*)&last[i * 4];
      float4 w1 = wm[i]; am += hh.x * w1.x + hh.y * w1.y + hh.z * w1.z + hh.w * w1.w;
      float4 w2 = wl[i]; al += hh.x * w2.x + hh.y * w2.y + hh.z * w2.z + hh.w * w2.w;
    }
    for (int i = 0; i < H / 4; i++) {
      float4 hh = *(const float4*)&sem[i * 4];
      float4 w1 = wm[H / 4 + i]; am += hh.x * w1.x + hh.y * w1.y + hh.z * w1.z + hh.w * w1.w;
      float4 w2 = wl[H / 4 + i]; al += hh.x * w2.x + hh.y * w2.y + hh.z * w2.z + hh.w * w2.w;
    }
    float muv = am + b_mu[j];
    float sgv = expf(al + b_ls[j]);
    float zv = muv + sgv * noise[b * L + j];
    out_tail[131072001ul + (size_t)b * L + j] = muv;
    out_tail[131076097ul + (size_t)b * L + j] = sgv;
    zf[b * L + j] = zv;
    zbf[j] = f2bf(zv);
  }
  __syncthreads();
  if (tid < L / 2) {                   // tagged h0 words for decoder (tag 0)
    u64 pw = ((unsigned)zbf[2 * tid + 1] << 16) | (u64)zbf[2 * tid];
    __hip_atomic_store(&hbw[b * (L / 2) + tid], pw,
                       __ATOMIC_RELAXED, __HIP_MEMORY_SCOPE_AGENT);
  }
  if (b == 0 && tid == 0) {
    int m = 0;
    for (int i = 0; i < B; i++) m = max(m, dec_len[i]);
    out_tail[131072000ul] = (float)m;
  }
}

extern "C" void kernel_launch(void* const* d_in, const int* in_sizes, int n_in,
                              void* d_out, int out_size, void* d_ws, size_t ws_size,
                              hipStream_t stream) {
  const float* emb     = (const float*)d_in[0];
  const float* eWih    = (const float*)d_in[1];
  const float* eWhh    = (const float*)d_in[2];
  const float* ebih    = (const float*)d_in[3];
  const float* ebhh    = (const float*)d_in[4];
  const float* dWih    = (const float*)d_in[5];
  const float* dWhh    = (const float*)d_in[6];
  const float* dbih    = (const float*)d_in[7];
  const float* dbhh    = (const float*)d_in[8];
  const float* W_mu    = (const float*)d_in[9];
  const float* b_mu    = (const float*)d_in[10];
  const float* W_ls    = (const float*)d_in[11];
  const float* b_ls    = (const float*)d_in[12];
  const float* W_fc    = (const float*)d_in[13];
  const float* b_fc    = (const float*)d_in[14];
  const float* noise   = (const float*)d_in[15];
  const int*   enc_ids = (const int*)d_in[16];
  const int*   enc_len = (const int*)d_in[17];
  const int*   dec_ids = (const int*)d_in[18];
  const int*   dec_len = (const int*)d_in[19];
  float* out = (float*)d_out;
  char* ws = (char*)d_ws;

  u16*   eWih_bf  = (u16*)(ws + 0);                    // 1,572,864
  u16*   dWih_bf  = (u16*)(ws + 1572864);              //   786,432
  u16*   Wfc_bf   = (u16*)(ws + 2359296);              // 16,384,000
  u64*   Hbuf_enc = (u64*)(ws + 18743296);             //    65,536 (2x4096 words)
  float* hlast    = (float*)(ws + 18808832);           //    32,768
  u64*   Hbuf_dec = (u64*)(ws + 18841600);             //    32,768 (2x2048 words)
  u16*   dec_out  = (u16*)(ws + 18874368);             // 2,097,152
  float* zf       = (float*)(ws + 20971520);           //    16,384

  char* ob = (char*)d_out;
  u16*   Xenc_bf = (u16*)(ob + 0);                     //  8,388,608
  u16*   Xdec_bf = (u16*)(ob + 8388608);               //  4,194,304
  float* GXE     = (float*)(ob + 12582912);            // 50,331,648
  float* GXD     = (float*)(ob + 62914560);            // 12,582,912
  float* out_enc = (float*)(ob + 75497472);            // 16,777,216

  hipMemsetAsync(Hbuf_enc, 0, 65536, stream);          // tags=0, h0=0 (both buffers)
  hipMemsetAsync(Hbuf_dec, 0, 32768, stream);          // tags=0 (k_middle sets z words)

  k_f2bf<<<384, 256, 0, stream>>>(eWih, eWih_bf, 786432);
  k_f2bf<<<192, 256, 0, stream>>>(dWih, dWih_bf, 393216);
  k_f2bf<<<4000, 256, 0, stream>>>(W_fc, Wfc_bf, 8192000);
  k_gather<<<2048, 256, 0, stream>>>(emb, enc_ids, Xenc_bf, B * TE);
  k_gather<<<1024, 256, 0, stream>>>(emb, dec_ids, Xdec_bf, B * TD);

  k_gemm_bt<<<dim3(12, 64), 256, 0, stream>>>(Xenc_bf, eWih_bf, ebih, GXE, B * TE, 3 * H, H);
  k_gemm_bt<<<dim3(6, 32), 256, 0, stream>>>(Xdec_bf, dWih_bf, dbih, GXD, B * TD, 3 * L, H);

  k_gru8<true, H, TE><<<16, 256, 0, stream>>>(GXE, eWhh, ebhh, enc_len, Hbuf_enc,
                                              nullptr, out_enc, nullptr, hlast);

  k_middle<<<B, 256, 0, stream>>>(out_enc, hlast, enc_len, W_mu, b_mu, W_ls, b_ls,
                                  noise, dec_len, out, zf, Hbuf_dec);

  k_gru8<false, L, TD><<<8, 256, 0, stream>>>(GXD, dWhh, dbhh, dec_len, Hbuf_dec,
                                              zf, nullptr, dec_out, nullptr);

  k_gemm_bt<<<dim3(250, 32), 256, 0, stream>>>(dec_out, Wfc_bf, b_fc, out, B * TD, NV, L);
}

// Round 10
// 2159.576 us; speedup vs baseline: 1.3739x; 1.3739x over previous
//
#include <hip/hip_runtime.h>
#include <hip/hip_bf16.h>
#include <stdint.h>

#define B 16
#define H 512
#define L 256
#define TE 512
#define TD 256
#define NV 32000

typedef __attribute__((ext_vector_type(8))) __bf16 bf16x8;
typedef __attribute__((ext_vector_type(4))) float f32x4;
typedef __attribute__((ext_vector_type(8))) unsigned short u16x8;
typedef __attribute__((ext_vector_type(4))) unsigned short u16x4;
typedef unsigned short u16;
typedef unsigned long long u64;

__device__ __forceinline__ u16 f2bf(float f) {
  unsigned u = __float_as_uint(f);
  u += 0x7fffu + ((u >> 16) & 1u);   // RNE
  return (u16)(u >> 16);
}
__device__ __forceinline__ float fast_sigmoid(float x) {
  return __builtin_amdgcn_rcpf(1.f + __expf(-x));
}
__device__ __forceinline__ float fast_tanh(float x) {
  float e = __expf(2.f * x);
  return 1.f - 2.f * __builtin_amdgcn_rcpf(e + 1.f);
}

__device__ __forceinline__ u16x8 pack8(float4 a, float4 c) {
  u16x8 r;
  r[0] = f2bf(a.x); r[1] = f2bf(a.y); r[2] = f2bf(a.z); r[3] = f2bf(a.w);
  r[4] = f2bf(c.x); r[5] = f2bf(c.y); r[6] = f2bf(c.z); r[7] = f2bf(c.w);
  return r;
}

// ---------------- f32 -> bf16 convert ----------------
__global__ __launch_bounds__(256) void k_f2bf(const float* __restrict__ in,
                                              u16* __restrict__ outp, long n) {
  long i = ((long)blockIdx.x * 256 + threadIdx.x) * 8;
  if (i + 8 > n) return;
  float4 a = *(const float4*)&in[i];
  float4 c = *(const float4*)&in[i + 4];
  *(u16x8*)&outp[i] = pack8(a, c);
}

// ---------------- embedding gather -> bf16 ----------------
__global__ __launch_bounds__(256) void k_gather(const float* __restrict__ emb,
                                                const int* __restrict__ ids,
                                                u16* __restrict__ X, int rows) {
  int gid = blockIdx.x * 256 + threadIdx.x;
  int m = gid >> 6, seg = gid & 63;           // 64 segs * 8 = 512 cols
  if (m >= rows) return;
  long src = (long)ids[m] * H + seg * 8;
  float4 a = *(const float4*)&emb[src];
  float4 c = *(const float4*)&emb[src + 4];
  *(u16x8*)&X[(long)m * H + seg * 8] = pack8(a, c);
}

// ---------------- bf16 MFMA GEMM tile body, C = A(MxK) * B^T(NxK) + bias ----
__device__ __forceinline__ void gemm_tile(char* smem, int bx, int by,
                                          const u16* __restrict__ A,
                                          const u16* __restrict__ Bw,
                                          const float* __restrict__ bias,
                                          float* __restrict__ C,
                                          int N, int K) {
  constexpr int LDSK = 72;
  u16* Al = (u16*)smem;
  u16* Bl = (u16*)(smem + 128 * LDSK * 2);
  const int tid = threadIdx.x;
  const int lane = tid & 63;
  const int wave = tid >> 6;
  const int wr = (wave >> 1) * 64, wc = (wave & 1) * 64;
  const long tM = (long)by * 128, tN = (long)bx * 128;
  const int r32 = tid >> 3;
  const int c8 = (tid & 7) * 8;
  const u16* Ag = A + (tM + r32) * (long)K + c8;
  const u16* Bg = Bw + (tN + r32) * (long)K + c8;
  const int fr = lane & 15;
  const int fq = lane >> 4;
  f32x4 acc[4][4] = {};

  for (int kb = 0; kb < K; kb += 64) {
    u16x8 ta0 = *(const u16x8*)(Ag + kb);
    u16x8 ta1 = *(const u16x8*)(Ag + 32 * (long)K + kb);
    u16x8 ta2 = *(const u16x8*)(Ag + 64 * (long)K + kb);
    u16x8 ta3 = *(const u16x8*)(Ag + 96 * (long)K + kb);
    u16x8 tb0 = *(const u16x8*)(Bg + kb);
    u16x8 tb1 = *(const u16x8*)(Bg + 32 * (long)K + kb);
    u16x8 tb2 = *(const u16x8*)(Bg + 64 * (long)K + kb);
    u16x8 tb3 = *(const u16x8*)(Bg + 96 * (long)K + kb);
    __syncthreads();
    *(u16x8*)&Al[(r32 +  0) * LDSK + c8] = ta0;
    *(u16x8*)&Al[(r32 + 32) * LDSK + c8] = ta1;
    *(u16x8*)&Al[(r32 + 64) * LDSK + c8] = ta2;
    *(u16x8*)&Al[(r32 + 96) * LDSK + c8] = ta3;
    *(u16x8*)&Bl[(r32 +  0) * LDSK + c8] = tb0;
    *(u16x8*)&Bl[(r32 + 32) * LDSK + c8] = tb1;
    *(u16x8*)&Bl[(r32 + 64) * LDSK + c8] = tb2;
    *(u16x8*)&Bl[(r32 + 96) * LDSK + c8] = tb3;
    __syncthreads();
#pragma unroll
    for (int ks = 0; ks < 2; ks++) {
      const int kcol = ks * 32 + fq * 8;
      bf16x8 av[4], bv[4];
#pragma unroll
      for (int mi = 0; mi < 4; mi++)
        av[mi] = __builtin_bit_cast(bf16x8, *(const u16x8*)&Al[(wr + mi * 16 + fr) * LDSK + kcol]);
#pragma unroll
      for (int ni = 0; ni < 4; ni++)
        bv[ni] = __builtin_bit_cast(bf16x8, *(const u16x8*)&Bl[(wc + ni * 16 + fr) * LDSK + kcol]);
#pragma unroll
      for (int mi = 0; mi < 4; mi++)
#pragma unroll
        for (int ni = 0; ni < 4; ni++)
          acc[mi][ni] = __builtin_amdgcn_mfma_f32_16x16x32_bf16(av[mi], bv[ni], acc[mi][ni], 0, 0, 0);
    }
  }
#pragma unroll
  for (int mi = 0; mi < 4; mi++) {
    long row = tM + wr + mi * 16 + fq * 4;
#pragma unroll
    for (int ni = 0; ni < 4; ni++) {
      long col = tN + wc + ni * 16 + fr;
      float bs = bias[col];
#pragma unroll
      for (int r = 0; r < 4; r++)
        C[(row + r) * (long)N + col] = acc[mi][ni][r] + bs;
    }
  }
}

__global__ __launch_bounds__(256) void k_gemm_bt(const u16* __restrict__ A,
                                                 const u16* __restrict__ Bw,
                                                 const float* __restrict__ bias,
                                                 float* __restrict__ C,
                                                 int M, int N, int K) {
  __shared__ __align__(16) char smem[2 * 128 * 72 * 2];
  gemm_tile(smem, blockIdx.x, blockIdx.y, A, Bw, bias, C, N, K);
}

// ---------------- persistent GRU v10: R4 protocol + fused side work ---------
// Blocks [0,ngru): R4's tagged data-flow GRU (16 WGs, no barriers, no fences).
// Blocks >= ngru (enc launch only): 192 GXD GEMM tiles + 240 W_fc f2bf WGs —
// independent finite work on otherwise-idle CUs; removes 2 serial launches.
template <bool ENC, int HD, int T, int UPW>
__global__ __launch_bounds__(256) void k_gru10(const float* __restrict__ GX,   // [B*T][3*HD]
                                               const float* __restrict__ Whh,  // [3*HD][HD]
                                               const float* __restrict__ bhh,
                                               const int* __restrict__ lens,
                                               u64* __restrict__ Hbuf,         // [2][16][HD/2] tagged
                                               const float* __restrict__ h0f,  // DEC: fp32 z
                                               float* __restrict__ out_f32,    // ENC: [B][T][HD]
                                               u16* __restrict__ out_bf,       // DEC: [B*T][HD]
                                               float* __restrict__ hlast,      // ENC: [B][HD]
                                               int ngru,
                                               const u16* __restrict__ sA,     // side GEMM A
                                               const u16* __restrict__ sB,     // side GEMM B
                                               const float* __restrict__ sbias,
                                               float* __restrict__ sC,
                                               const float* __restrict__ cvt_in,
                                               u16* __restrict__ cvt_out) {
  constexpr int ROWS = 3 * UPW;
  constexpr int NT = ROWS / 16;
  constexpr int NA = (NT + 3) / 4;
  constexpr int LDH = HD + 8;
  constexpr int CT = 16 * UPW / 2;     // combine threads: enc 256, dec 128
  constexpr int WPB = HD / 2;          // words per batch row
  constexpr int NWORD = 16 * WPB;      // words per buffer
  constexpr int PW = NWORD / 256;      // words polled per thread (enc 16, dec 8)
  constexpr size_t WB = (size_t)ROWS * LDH * 2;
  constexpr size_t HBB = (size_t)16 * LDH * 2;
  constexpr size_t GB = (size_t)3 * 16 * UPW * 4;
  constexpr size_t GRUB = WB + HBB + GB;
  constexpr size_t SMEMB = GRUB > 36864 ? GRUB : 36864;
  __shared__ __align__(16) char smem[SMEMB];

  // ---- side-work blocks (enc launch only) ----
  if ((int)blockIdx.x >= ngru) {
    int sb = (int)blockIdx.x - ngru;
    if (sb < 192) {                    // GXD GEMM: M=4096, N=768, K=512
      gemm_tile(smem, sb % 6, sb / 6, sA, sB, sbias, sC, 3 * L, H);
    } else {                           // W_fc f2bf: 8,192,000 elems
      int sbf = sb - 192;
      for (long base = (long)sbf * 2048 + (long)threadIdx.x * 8;
           base < (long)NV * L; base += 240L * 2048) {
        float4 a = *(const float4*)&cvt_in[base];
        float4 c = *(const float4*)&cvt_in[base + 4];
        *(u16x8*)&cvt_out[base] = pack8(a, c);
      }
    }
    return;
  }

  u16 (*w_lds)[LDH] = (u16(*)[LDH])smem;
  u16 (*h_lds)[LDH] = (u16(*)[LDH])(smem + WB);
  float (*g_lds)[16][UPW] = (float(*)[16][UPW])(smem + WB + HBB);

  const int tid = threadIdx.x;
  const int u0 = blockIdx.x * UPW;
  const int lane = tid & 63, wv = tid >> 6;
  const int fr = lane & 15, fq = lane >> 4;

  // one-time: Whh slice -> bf16 LDS
  for (int i = tid; i < ROWS * HD / 4; i += 256) {
    int rr = i / (HD / 4), c = (i % (HD / 4)) * 4;
    int grow = (rr / UPW) * HD + u0 + (rr % UPW);
    float4 v = *(const float4*)&Whh[(long)grow * HD + c];
    u16x4 p; p[0] = f2bf(v.x); p[1] = f2bf(v.y); p[2] = f2bf(v.z); p[3] = f2bf(v.w);
    *(u16x4*)&w_lds[rr][c] = p;
  }
  int tmax = 1;
#pragma unroll
  for (int i = 0; i < 16; i++) tmax = max(tmax, lens[i]);

  const bool act = tid < CT;
  const int cb = tid / (UPW / 2);      // batch (0..15 for act threads)
  const int up = tid % (UPW / 2);      // unit-pair
  const int uu = u0 + 2 * up;
  const int len_b = lens[act ? cb : 0];
  float bh[3][2], hold[2];
#pragma unroll
  for (int g = 0; g < 3; g++)
#pragma unroll
    for (int j = 0; j < 2; j++) bh[g][j] = act ? bhh[g * HD + uu + j] : 0.f;
#pragma unroll
  for (int j = 0; j < 2; j++)
    hold[j] = (ENC || !act) ? 0.f : h0f[cb * HD + uu + j];
  __syncthreads();

  for (int t = 0; ; t++) {
    const u64* Hc = Hbuf + (size_t)(t & 1) * NWORD;
    u64* Hn = Hbuf + (size_t)((t + 1) & 1) * NWORD;
    // gx(t): issued now, consumed in phase C
    float gxv[3][2];
    if (act) {
#pragma unroll
      for (int g = 0; g < 3; g++)
#pragma unroll
        for (int j = 0; j < 2; j++)
          gxv[g][j] = GX[((size_t)cb * T + t) * 3 * HD + g * HD + uu + j];
    }
    // ---- phase A: coalesced poll of tagged h words until fresh, stage LDS ----
    const unsigned want = (unsigned)t;
    u64 vv[PW];
#pragma unroll
    for (int i = 0; i < PW; i++)
      vv[i] = __hip_atomic_load(&Hc[i * 256 + tid], __ATOMIC_RELAXED, __HIP_MEMORY_SCOPE_AGENT);
    for (;;) {
      bool ok = true;
#pragma unroll
      for (int i = 0; i < PW; i++) ok &= ((unsigned)(vv[i] >> 32) == want);
      if (ok) break;
#pragma unroll
      for (int i = 0; i < PW; i++)
        if ((unsigned)(vv[i] >> 32) != want)
          vv[i] = __hip_atomic_load(&Hc[i * 256 + tid], __ATOMIC_RELAXED, __HIP_MEMORY_SCOPE_AGENT);
    }
#pragma unroll
    for (int i = 0; i < PW; i++) {
      int w = i * 256 + tid;
      *(unsigned*)&h_lds[w / WPB][(w % WPB) * 2] = (unsigned)vv[i];
    }
    __syncthreads();
    // ---- phase B: gh = h @ Whh^T via MFMA ----
    f32x4 acc[NA];
#pragma unroll
    for (int a = 0; a < NA; a++) {
      int ti = wv + a * 4;
      if (ti < NT) {
        f32x4 ac = {};
#pragma unroll
        for (int kk = 0; kk < HD / 32; kk++) {
          int kc = kk * 32 + fq * 8;
          bf16x8 av = __builtin_bit_cast(bf16x8, *(const u16x8*)&h_lds[fr][kc]);
          bf16x8 bv = __builtin_bit_cast(bf16x8, *(const u16x8*)&w_lds[ti * 16 + fr][kc]);
          ac = __builtin_amdgcn_mfma_f32_16x16x32_bf16(av, bv, ac, 0, 0, 0);
        }
        acc[a] = ac;
      }
    }
#pragma unroll
    for (int a = 0; a < NA; a++) {
      int ti = wv + a * 4;
      if (ti < NT) {
        int g = (ti * 16) / UPW, ul = (ti * 16) % UPW;
#pragma unroll
        for (int r = 0; r < 4; r++)
          g_lds[g][fq * 4 + r][ul + fr] = acc[a][r];
      }
    }
    __syncthreads();
    // ---- phase C: gates + h update + tagged publish ----
    if (act) {
      const bool val = t < len_b;
      u16 pk[2]; float hnv[2];
#pragma unroll
      for (int j = 0; j < 2; j++) {
        int u = 2 * up + j;
        float rr_ = fast_sigmoid(g_lds[0][cb][u] + bh[0][j] + gxv[0][j]);
        float zz  = fast_sigmoid(g_lds[1][cb][u] + bh[1][j] + gxv[1][j]);
        float nn  = fast_tanh(gxv[2][j] + rr_ * (g_lds[2][cb][u] + bh[2][j]));
        float hnew = (1.f - zz) * nn + zz * hold[j];
        float hk = val ? hnew : hold[j];
        hold[j] = hk;
        pk[j] = f2bf(hk);
        hnv[j] = val ? hnew : 0.f;
      }
      u64 pw = ((u64)(unsigned)(t + 1) << 32) | ((unsigned)pk[1] << 16) | pk[0];
      __hip_atomic_store(&Hn[cb * WPB + (uu >> 1)], pw,
                         __ATOMIC_RELAXED, __HIP_MEMORY_SCOPE_AGENT);
      if constexpr (ENC) {
        *(float2*)&out_f32[((size_t)cb * T + t) * HD + uu] = make_float2(hnv[0], hnv[1]);
      } else {
        *(unsigned*)&out_bf[((size_t)cb * T + t) * HD + uu] =
            ((unsigned)f2bf(hnv[1]) << 16) | f2bf(hnv[0]);
      }
    }
    if (t + 1 >= tmax) break;
  }

  // ---- epilogue: hlast + zero-fill t in [tmax, T) ----
  if (act) {
    if constexpr (ENC) {
      *(float2*)&hlast[cb * HD + uu] = make_float2(hold[0], hold[1]);
      for (int t2 = tmax; t2 < T; t2++)
        *(float2*)&out_f32[((size_t)cb * T + t2) * HD + uu] = make_float2(0.f, 0.f);
    } else {
      for (int t2 = tmax; t2 < T; t2++)
        *(unsigned*)&out_bf[((size_t)cb * T + t2) * HD + uu] = 0u;
    }
  }
}

// ---------------- attention pooling + mu/sigma/z + dec_max_len ----------------
__global__ __launch_bounds__(256) void k_middle(const float* __restrict__ out_enc,
                                                const float* __restrict__ hlast,
                                                const int* __restrict__ enc_len,
                                                const float* __restrict__ W_mu,
                                                const float* __restrict__ b_mu,
                                                const float* __restrict__ W_ls,
                                                const float* __restrict__ b_ls,
                                                const float* __restrict__ noise,
                                                const int* __restrict__ dec_len,
                                                float* __restrict__ out_tail,
                                                float* __restrict__ zf,
                                                u64* __restrict__ hbw) {
  const int b = blockIdx.x, tid = threadIdx.x;
  __shared__ float last[H], first[H], sfw[TE], sbw[TE], alpha[TE], sem[H];
  __shared__ float redA[256], redB[256];
  __shared__ u16 zbf[L];
  const int len = enc_len[b];
  for (int i = tid; i < H; i += 256) {
    last[i] = hlast[b * H + i];
    first[i] = out_enc[((size_t)b * TE) * H + i];
  }
  __syncthreads();
  for (int t = tid; t < TE; t += 256) {
    float afw = 0.f, abw = 0.f;
    if (t < len) {
      const float4* op = (const float4*)&out_enc[((size_t)b * TE + t) * H];
      for (int i = 0; i < H / 4; i++) {
        float4 o = op[i];
        float4 l = *(const float4*)&last[i * 4];
        float4 f = *(const float4*)&first[i * 4];
        afw += o.x * l.x + o.y * l.y + o.z * l.z + o.w * l.w;
        abw += o.x * f.x + o.y * f.y + o.z * f.z + o.w * f.w;
      }
    }
    sfw[t] = afw; sbw[t] = abw;
  }
  __syncthreads();
  float mfw = -3e38f, mbw = -3e38f;
  for (int t = tid; t < len; t += 256) { mfw = fmaxf(mfw, sfw[t]); mbw = fmaxf(mbw, sbw[t]); }
  redA[tid] = mfw; redB[tid] = mbw; __syncthreads();
  for (int s = 128; s > 0; s >>= 1) {
    if (tid < s) { redA[tid] = fmaxf(redA[tid], redA[tid + s]); redB[tid] = fmaxf(redB[tid], redB[tid + s]); }
    __syncthreads();
  }
  const float Mfw = redA[0], Mbw = redB[0];
  __syncthreads();
  float tfw = 0.f, tbw = 0.f;
  for (int t = tid; t < len; t += 256) {
    float e1 = expf(sfw[t] - Mfw); sfw[t] = e1; tfw += e1;
    float e2 = expf(sbw[t] - Mbw); sbw[t] = e2; tbw += e2;
  }
  redA[tid] = tfw; redB[tid] = tbw; __syncthreads();
  for (int s = 128; s > 0; s >>= 1) {
    if (tid < s) { redA[tid] += redA[tid + s]; redB[tid] += redB[tid + s]; }
    __syncthreads();
  }
  const float ifw = 0.5f / redA[0], ibw = 0.5f / redB[0];
  __syncthreads();
  for (int t = tid; t < TE; t += 256) alpha[t] = (t < len) ? (sfw[t] * ifw + sbw[t] * ibw) : 0.f;
  __syncthreads();
  for (int d = tid; d < H; d += 256) {
    float s = 0.f;
    for (int t = 0; t < len; t++) s += alpha[t] * out_enc[((size_t)b * TE + t) * H + d];
    sem[d] = s;
  }
  __syncthreads();
  {
    const int j = tid;  // 256 == L
    const float4* wm = (const float4*)&W_mu[(size_t)j * 2 * H];
    const float4* wl = (const float4*)&W_ls[(size_t)j * 2 * H];
    float am = 0.f, al = 0.f;
    for (int i = 0; i < H / 4; i++) {
      float4 hh = *(const float4*)&last[i * 4];
      float4 w1 = wm[i]; am += hh.x * w1.x + hh.y * w1.y + hh.z * w1.z + hh.w * w1.w;
      float4 w2 = wl[i]; al += hh.x * w2.x + hh.y * w2.y + hh.z * w2.z + hh.w * w2.w;
    }
    for (int i = 0; i < H / 4; i++) {
      float4 hh = *(const float4*)&sem[i * 4];
      float4 w1 = wm[H / 4 + i]; am += hh.x * w1.x + hh.y * w1.y + hh.z * w1.z + hh.w * w1.w;
      float4 w2 = wl[H / 4 + i]; al += hh.x * w2.x + hh.y * w2.y + hh.z * w2.z + hh.w * w2.w;
    }
    float muv = am + b_mu[j];
    float sgv = expf(al + b_ls[j]);
    float zv = muv + sgv * noise[b * L + j];
    out_tail[131072001ul + (size_t)b * L + j] = muv;
    out_tail[131076097ul + (size_t)b * L + j] = sgv;
    zf[b * L + j] = zv;
    zbf[j] = f2bf(zv);
  }
  __syncthreads();
  if (tid < L / 2) {                   // tagged h0 words for decoder (tag 0)
    u64 pw = ((unsigned)zbf[2 * tid + 1] << 16) | (u64)zbf[2 * tid];
    __hip_atomic_store(&hbw[b * (L / 2) + tid], pw,
                       __ATOMIC_RELAXED, __HIP_MEMORY_SCOPE_AGENT);
  }
  if (b == 0 && tid == 0) {
    int m = 0;
    for (int i = 0; i < B; i++) m = max(m, dec_len[i]);
    out_tail[131072000ul] = (float)m;
  }
}

extern "C" void kernel_launch(void* const* d_in, const int* in_sizes, int n_in,
                              void* d_out, int out_size, void* d_ws, size_t ws_size,
                              hipStream_t stream) {
  const float* emb     = (const float*)d_in[0];
  const float* eWih    = (const float*)d_in[1];
  const float* eWhh    = (const float*)d_in[2];
  const float* ebih    = (const float*)d_in[3];
  const float* ebhh    = (const float*)d_in[4];
  const float* dWih    = (const float*)d_in[5];
  const float* dWhh    = (const float*)d_in[6];
  const float* dbih    = (const float*)d_in[7];
  const float* dbhh    = (const float*)d_in[8];
  const float* W_mu    = (const float*)d_in[9];
  const float* b_mu    = (const float*)d_in[10];
  const float* W_ls    = (const float*)d_in[11];
  const float* b_ls    = (const float*)d_in[12];
  const float* W_fc    = (const float*)d_in[13];
  const float* b_fc    = (const float*)d_in[14];
  const float* noise   = (const float*)d_in[15];
  const int*   enc_ids = (const int*)d_in[16];
  const int*   enc_len = (const int*)d_in[17];
  const int*   dec_ids = (const int*)d_in[18];
  const int*   dec_len = (const int*)d_in[19];
  float* out = (float*)d_out;
  char* ws = (char*)d_ws;

  u16*   eWih_bf  = (u16*)(ws + 0);                    // 1,572,864
  u16*   dWih_bf  = (u16*)(ws + 1572864);              //   786,432
  u16*   Wfc_bf   = (u16*)(ws + 2359296);              // 16,384,000
  u64*   Hbuf_enc = (u64*)(ws + 18743296);             //    65,536 (2x4096 words)
  float* hlast    = (float*)(ws + 18808832);           //    32,768
  u64*   Hbuf_dec = (u64*)(ws + 18841600);             //    32,768 (2x2048 words)
  u16*   dec_out  = (u16*)(ws + 18874368);             // 2,097,152
  float* zf       = (float*)(ws + 20971520);           //    16,384

  char* ob = (char*)d_out;
  u16*   Xenc_bf = (u16*)(ob + 0);                     //  8,388,608
  u16*   Xdec_bf = (u16*)(ob + 8388608);               //  4,194,304
  float* GXE     = (float*)(ob + 12582912);            // 50,331,648
  float* GXD     = (float*)(ob + 62914560);            // 12,582,912
  float* out_enc = (float*)(ob + 75497472);            // 16,777,216

  hipMemsetAsync(Hbuf_enc, 0, 65536, stream);          // tags=0, h0=0 (both buffers)
  hipMemsetAsync(Hbuf_dec, 0, 32768, stream);          // tags=0 (k_middle sets z words)

  k_f2bf<<<384, 256, 0, stream>>>(eWih, eWih_bf, 786432);
  k_f2bf<<<192, 256, 0, stream>>>(dWih, dWih_bf, 393216);
  k_gather<<<2048, 256, 0, stream>>>(emb, enc_ids, Xenc_bf, B * TE);
  k_gather<<<1024, 256, 0, stream>>>(emb, dec_ids, Xdec_bf, B * TD);

  k_gemm_bt<<<dim3(12, 64), 256, 0, stream>>>(Xenc_bf, eWih_bf, ebih, GXE, B * TE, 3 * H, H);

  // enc GRU (blocks 0-15) + fused side work: GXD GEMM (16-207), W_fc f2bf (208-447)
  k_gru10<true, H, TE, 32><<<448, 256, 0, stream>>>(GXE, eWhh, ebhh, enc_len, Hbuf_enc,
                                                    nullptr, out_enc, nullptr, hlast,
                                                    16, Xdec_bf, dWih_bf, dbih, GXD,
                                                    W_fc, Wfc_bf);

  k_middle<<<B, 256, 0, stream>>>(out_enc, hlast, enc_len, W_mu, b_mu, W_ls, b_ls,
                                  noise, dec_len, out, zf, Hbuf_dec);

  k_gru10<false, L, TD, 16><<<16, 256, 0, stream>>>(GXD, dWhh, dbhh, dec_len, Hbuf_dec,
                                                    zf, nullptr, dec_out, nullptr,
                                                    16, nullptr, nullptr, nullptr, nullptr,
                                                    nullptr, nullptr);

  k_gemm_bt<<<dim3(250, 32), 256, 0, stream>>>(dec_out, Wfc_bf, b_fc, out, B * TD, NV, L);
}